// Round 1
// baseline (16.889 us; speedup 1.0000x reference)
//
#include <hip/hip_runtime.h>

#define BATCH_N 8192
#define NQ 10
#define CD 138      // comb dim = 128 + 10
#define CPAD 140    // padded to multiple of 4 floats (16B rows)
#define RT 32       // rows per block
#define NJ 40       // 4 gates * 10 qubits

__global__ __launch_bounds__(256) void qlstm_kernel(
    const float* __restrict__ x,  const float* __restrict__ hx, const float* __restrict__ cx,
    const float* __restrict__ Wf, const float* __restrict__ bf,
    const float* __restrict__ Wi, const float* __restrict__ bi,
    const float* __restrict__ Wu, const float* __restrict__ bu,
    const float* __restrict__ Wo, const float* __restrict__ bo,
    float* __restrict__ out)
{
    __shared__ float sW[NJ][CPAD];      // 22.4 KB
    __shared__ float sComb[RT][CPAD];   // 17.9 KB
    __shared__ float sB[NJ];
    __shared__ float sTheta[RT][44];
    __shared__ float sGate[4][RT][NQ];

    const int tid = threadIdx.x;
    const int r0  = blockIdx.x * RT;

    const float* Ws[4] = {Wf, Wi, Wu, Wo};
    const float* bs[4] = {bf, bi, bu, bo};

    // ---- stage weights into LDS (gate-major rows: j = g*10+q) ----
    #pragma unroll
    for (int g = 0; g < 4; ++g) {
        for (int idx = tid; idx < NQ * CD; idx += 256) {
            int j = idx / CD;
            int k = idx - j * CD;
            sW[g * NQ + j][k] = Ws[g][idx];
        }
    }
    if (tid < 2 * NJ) sW[tid >> 1][CD + (tid & 1)] = 0.f;   // zero pad cols 138,139
    if (tid < NJ)     sB[tid] = bs[tid / NQ][tid % NQ];

    // ---- stage comb tile: x rows (float4, coalesced) + hx cols ----
    {
        const float4* x4 = (const float4*)(x + (size_t)r0 * 128);
        for (int idx = tid; idx < RT * 32; idx += 256) {   // 32 float4 per row
            int row = idx >> 5;
            int c4  = idx & 31;
            float4 v = x4[idx];
            *(float4*)&sComb[row][c4 * 4] = v;
        }
    }
    for (int idx = tid; idx < RT * NQ; idx += 256) {
        int row = idx / NQ;
        int q   = idx - row * NQ;
        sComb[row][128 + q] = hx[(size_t)r0 * NQ + idx];
    }
    if (tid < 2 * RT) sComb[tid >> 1][CD + (tid & 1)] = 0.f; // zero pad cols 138,139

    __syncthreads();

    // ---- phase A: theta[r][j] = comb[r] . W[j] + b[j] ----
    {
        const int r  = tid & 31;
        const int j0 = (tid >> 5) * 5;     // 8 groups of 5 outputs
        float acc[5];
        #pragma unroll
        for (int jj = 0; jj < 5; ++jj) acc[jj] = sB[j0 + jj];
        for (int k4 = 0; k4 < CPAD / 4; ++k4) {
            float4 xv = *(const float4*)&sComb[r][k4 * 4];
            #pragma unroll
            for (int jj = 0; jj < 5; ++jj) {
                float4 wv = *(const float4*)&sW[j0 + jj][k4 * 4];
                acc[jj] = fmaf(xv.x, wv.x, acc[jj]);
                acc[jj] = fmaf(xv.y, wv.y, acc[jj]);
                acc[jj] = fmaf(xv.z, wv.z, acc[jj]);
                acc[jj] = fmaf(xv.w, wv.w, acc[jj]);
            }
        }
        #pragma unroll
        for (int jj = 0; jj < 5; ++jj) sTheta[r][j0 + jj] = acc[jj];
    }
    __syncthreads();

    // ---- phase B: closed-form circuit  z_q = prod_{k<=q, k=q mod 2} cos(theta_k)
    //      then sigmoid (gates f,i,o) / tanh (gate u) ----
    if (tid < 4 * RT) {
        const int r = tid & 31;
        const int g = tid >> 5;            // 0:f 1:i 2:u 3:o
        float z[NQ];
        #pragma unroll
        for (int q = 0; q < NQ; ++q) {
            float c = cosf(sTheta[r][g * NQ + q]);
            z[q] = (q < 2) ? c : z[q - 2] * c;
        }
        #pragma unroll
        for (int q = 0; q < NQ; ++q) {
            float zz = z[q];
            float val = (g == 2) ? tanhf(zz) : 1.f / (1.f + expf(-zz));
            sGate[g][r][q] = val;
        }
    }
    __syncthreads();

    // ---- phase C: LSTM combine, coalesced loads/stores ----
    const float* fG = &sGate[0][0][0];
    const float* iG = &sGate[1][0][0];
    const float* gG = &sGate[2][0][0];
    const float* oG = &sGate[3][0][0];
    for (int idx = tid; idx < RT * NQ; idx += 256) {
        float fv  = fG[idx];
        float iv  = iG[idx];
        float gv  = gG[idx];
        float ov  = oG[idx];
        float cxv = cx[(size_t)r0 * NQ + idx];
        float cn  = fv * cxv + iv * gv;
        float hn  = ov * tanhf(cn);
        out[(size_t)r0 * NQ + idx] = hn;                               // h_new
        out[(size_t)BATCH_N * NQ + (size_t)r0 * NQ + idx] = cn;        // c_new
    }
}

extern "C" void kernel_launch(void* const* d_in, const int* in_sizes, int n_in,
                              void* d_out, int out_size, void* d_ws, size_t ws_size,
                              hipStream_t stream) {
    const float* x  = (const float*)d_in[0];
    const float* hx = (const float*)d_in[1];
    const float* cx = (const float*)d_in[2];
    const float* Wf = (const float*)d_in[3];
    const float* bf = (const float*)d_in[4];
    const float* Wi = (const float*)d_in[5];
    const float* bi = (const float*)d_in[6];
    const float* Wu = (const float*)d_in[7];
    const float* bu = (const float*)d_in[8];
    const float* Wo = (const float*)d_in[9];
    const float* bo = (const float*)d_in[10];
    float* out = (float*)d_out;

    dim3 grid(BATCH_N / RT);
    dim3 block(256);
    hipLaunchKernelGGL(qlstm_kernel, grid, block, 0, stream,
                       x, hx, cx, Wf, bf, Wi, bi, Wu, bu, Wo, bo, out);
}